// Round 6
// baseline (132.488 us; speedup 1.0000x reference)
//
#include <hip/hip_runtime.h>

#define HW 50176            // 224*224
#define HW2 25088           // HW/2 (uint = 2 f16 per frame row unit)
#define HW4 12544           // HW/4 (float4 / uint2 per frame)
#define TT 64
#define NB1 3136            // 8 b × 4 tc × 98 hw-blocks (98*256*2 = HW)
#define NB3 3808            // 8 b × 68 t × 7 segs (7*1792 = 12544 = HW4)
#define SUMW 0.9999f        // 0.2989+0.587+0.114

__device__ __forceinline__ float gelu_erf(float x) {
    return 0.5f * x * (1.0f + erff(0.70710678f * x));
}
__device__ __forceinline__ float fast_rcp(float v) {
    float r; asm("v_rcp_f32 %0, %1" : "=v"(r) : "v"(v)); return r;
}
__device__ __forceinline__ float gelu_fast(float x) {
    // tanh-form gelu; max |err| ~3e-3 vs erf form (cancels via normalize)
    float x2 = x * x;
    float e = exp2f(-x * fmaf(0.1029433f, x2, 2.3022078f));
    return x * fast_rcp(1.0f + e);
}
// order-preserving float <-> uint encoding for atomicMin/Max
__device__ __forceinline__ unsigned encf(float f) {
    unsigned u = __float_as_uint(f);
    return (u & 0x80000000u) ? ~u : (u | 0x80000000u);
}
__device__ __forceinline__ float decf(unsigned u) {
    unsigned b = (u & 0x80000000u) ? (u ^ 0x80000000u) : ~u;
    return __uint_as_float(b);
}
__device__ __forceinline__ unsigned pk_min_f16(unsigned a, unsigned b) {
    unsigned r; asm("v_pk_min_f16 %0, %1, %2" : "=v"(r) : "v"(a), "v"(b)); return r;
}
__device__ __forceinline__ unsigned pack2(float lo, float hi) {
    auto p = __builtin_amdgcn_cvt_pkrtz(lo, hi);
    return __builtin_bit_cast(unsigned, p);
}
__device__ __forceinline__ unsigned mm2(float2 r) {   // packed (min r, min -r) over 2 px
    return pk_min_f16(pack2(r.x, -r.x), pack2(r.y, -r.y));
}
__device__ __forceinline__ float2 re_full2(float2 w0, float2 w1, float2 w3, float2 w4) {
    float2 r;
    r.x = fmaf(4.f, w4.x - w0.x, 2.f * (w3.x - w1.x));
    r.y = fmaf(4.f, w4.y - w0.y, 2.f * (w3.y - w1.y));
    return r;
}

// Pass 1 (fused): 2 px/thread, 16-window t-chunk, 3 channels.
// Tracks packed-f16 (min re, min -re) per t AND writes gs = sum_c w_c*gelu(re_c) as 2xf16.
template<bool WGS>
__global__ __launch_bounds__(256, 6) void k_pass1(const float* __restrict__ x,
                                                  unsigned* __restrict__ gmm,
                                                  unsigned* __restrict__ gs) {
    __shared__ unsigned smin[16], smax[16];
    const int tid = threadIdx.x;
    if (tid < 16) { smin[tid] = 0xFFFFFFFFu; smax[tid] = 0u; }
    __syncthreads();

    const int bid = blockIdx.x;
    const int b   = bid / 392;             // 392 = 4*98
    const int rem = bid - b * 392;
    const int tc  = rem / 98;              // t-chunk 0..3
    const int hwb = rem - tc * 98;
    const int t0  = tc * 16;
    const int hw  = (hwb * 256 + tid) * 2;
    const float* xa = x + ((size_t)(b * 3 + 0) * TT + t0) * (size_t)HW + hw;
    const float* xb = x + ((size_t)(b * 3 + 1) * TT + t0) * (size_t)HW + hw;
    const float* xc = x + ((size_t)(b * 3 + 2) * TT + t0) * (size_t)HW + hw;
    unsigned* gp = gs + ((size_t)b * TT + t0) * (size_t)HW2 + (hwb * 256 + tid);

    unsigned acc[16];
    #pragma unroll
    for (int j = 0; j < 16; ++j) acc[j] = 0x7BFF7BFFu;   // (65504, 65504)

    #define LDA(f) (*(const float2*)(xa + (size_t)(f) * HW))
    #define LDB(f) (*(const float2*)(xb + (size_t)(f) * HW))
    #define LDC(f) (*(const float2*)(xc + (size_t)(f) * HW))

    auto step = [&](float2 ra, float2 rb, float2 rc, int j) {
        acc[j] = pk_min_f16(acc[j], pk_min_f16(pk_min_f16(mm2(ra), mm2(rb)), mm2(rc)));
        if constexpr (WGS) {
            float gx = fmaf(0.114f, gelu_fast(rc.x), fmaf(0.587f, gelu_fast(rb.x), 0.2989f * gelu_fast(ra.x)));
            float gy = fmaf(0.114f, gelu_fast(rc.y), fmaf(0.587f, gelu_fast(rb.y), 0.2989f * gelu_fast(ra.y)));
            gp[(size_t)j * HW2] = pack2(gx, gy);
        }
    };

    float2 a0 = LDA(0), a1 = LDA(1), a2 = LDA(2), a3 = LDA(3), a4 = LDA(4), pa = LDA(5);
    float2 b0 = LDB(0), b1 = LDB(1), b2 = LDB(2), b3 = LDB(3), b4 = LDB(4), pb = LDB(5);
    float2 c0 = LDC(0), c1 = LDC(1), c2 = LDC(2), c3 = LDC(3), c4 = LDC(4), pc = LDC(5);

    if (tc < 3) {
        #pragma unroll
        for (int j = 0; j < 16; ++j) {     // windows t0+j, all full-weight
            step(re_full2(a0, a1, a3, a4), re_full2(b0, b1, b3, b4), re_full2(c0, c1, c3, c4), j);
            a0 = a1; a1 = a2; a2 = a3; a3 = a4; a4 = pa;
            b0 = b1; b1 = b2; b2 = b3; b3 = b4; b4 = pb;
            c0 = c1; c1 = c2; c2 = c3; c3 = c4; c4 = pc;
            if (j < 14) { pa = LDA(j + 6); pb = LDB(j + 6); pc = LDC(j + 6); }
        }
    } else {
        #pragma unroll
        for (int j = 0; j < 16; ++j) {     // windows 48+j; tails at 60..63
            float2 ra, rb, rc;
            if (j < 12) {
                ra = re_full2(a0, a1, a3, a4); rb = re_full2(b0, b1, b3, b4); rc = re_full2(c0, c1, c3, c4);
            } else if (j == 12) {          // t=60: weights -3,-1,1,3
                ra.x = fmaf(3.f, a3.x - a0.x, a2.x - a1.x); ra.y = fmaf(3.f, a3.y - a0.y, a2.y - a1.y);
                rb.x = fmaf(3.f, b3.x - b0.x, b2.x - b1.x); rb.y = fmaf(3.f, b3.y - b0.y, b2.y - b1.y);
                rc.x = fmaf(3.f, c3.x - c0.x, c2.x - c1.x); rc.y = fmaf(3.f, c3.y - c0.y, c2.y - c1.y);
            } else if (j == 13) {          // t=61: -2,0,2
                ra.x = 2.f*(a2.x-a0.x); ra.y = 2.f*(a2.y-a0.y);
                rb.x = 2.f*(b2.x-b0.x); rb.y = 2.f*(b2.y-b0.y);
                rc.x = 2.f*(c2.x-c0.x); rc.y = 2.f*(c2.y-c0.y);
            } else if (j == 14) {          // t=62: -1,1
                ra.x = a1.x-a0.x; ra.y = a1.y-a0.y;
                rb.x = b1.x-b0.x; rb.y = b1.y-b0.y;
                rc.x = c1.x-c0.x; rc.y = c1.y-c0.y;
            } else {                       // t=63: weight 0
                ra.x = ra.y = 0.f; rb = ra; rc = ra;
            }
            step(ra, rb, rc, j);
            a0 = a1; a1 = a2; a2 = a3; a3 = a4; a4 = pa;
            b0 = b1; b1 = b2; b2 = b3; b3 = b4; b4 = pb;
            c0 = c1; c1 = c2; c2 = c3; c3 = c4; c4 = pc;
            if (j < 10) { pa = LDA(j + 6); pb = LDB(j + 6); pc = LDC(j + 6); }
        }
    }
    #undef LDA
    #undef LDB
    #undef LDC

    // wave butterfly reduce; lane j keeps window t0+j
    const int lane = tid & 63;
    unsigned keep = 0x7BFF7BFFu;
    #pragma unroll
    for (int j = 0; j < 16; ++j) {
        unsigned a = acc[j];
        #pragma unroll
        for (int off = 32; off; off >>= 1)
            a = pk_min_f16(a, (unsigned)__shfl_xor((int)a, off, 64));
        if (lane == j) keep = a;
    }

    if (lane < 16) {
        union { unsigned u; _Float16 h[2]; } cv; cv.u = keep;
        const float amin = (float)cv.h[0];
        const float amax = -(float)cv.h[1];
        const float g0 = gelu_erf(amin), g1 = gelu_erf(amax);
        const float gmax = fmaxf(g0, g1);
        const float XSTAR = -0.7517916f;             // argmin of gelu
        float gmin;
        if (amin >= XSTAR)      gmin = g0;
        else if (amax <= XSTAR) gmin = g1;
        else                    gmin = fminf(gelu_erf(XSTAR), fminf(g0, g1));
        atomicMin(&smin[lane], encf(gmin));
        atomicMax(&smax[lane], encf(gmax));
    }
    __syncthreads();
    if (tid < 16)            atomicMin(&gmm[t0 + tid], smin[tid]);
    else if (tid < 32)       atomicMax(&gmm[TT + t0 + tid - 16], smax[tid - 16]);
}

// Pass 3: out[b,t] = (t<4) ? 0 : gs[b,t-4]*A + B, A/B derived from gmm inline.
__global__ __launch_bounds__(256) void k_pass3(const unsigned* __restrict__ gs,
                                               const unsigned* __restrict__ gmm,
                                               float* __restrict__ out) {
    const int bid = blockIdx.x;
    const int b   = bid / 476;             // 476 = 68*7
    const int r   = bid - b * 476;
    const int t   = r / 7;
    const int seg = r - t * 7;
    const int base4 = seg * 1792 + threadIdx.x;    // float4 index within frame
    float4* op = (float4*)out + ((size_t)b * 68 + t) * HW4 + base4;

    if (t < 4) {
        float4 z = make_float4(0.f, 0.f, 0.f, 0.f);
        #pragma unroll
        for (int k = 0; k < 7; ++k) op[k * 256] = z;
        return;
    }
    const int tm = t - 4;
    const float mn = decf(gmm[tm]);
    const float mx = decf(gmm[TT + tm]) - mn;
    const float inv = fast_rcp((mx != 0.f) ? mx : 1e-5f);
    const float A = inv, Bv = -mn * SUMW * inv;

    const uint2* gpp = (const uint2*)gs + ((size_t)b * TT + tm) * HW4 + base4;
    #pragma unroll
    for (int k = 0; k < 7; ++k) {
        uint2 v = gpp[k * 256];
        union { unsigned u; _Float16 h[2]; } lo, hi; lo.u = v.x; hi.u = v.y;
        float4 o;
        o.x = fmaf((float)lo.h[0], A, Bv);
        o.y = fmaf((float)lo.h[1], A, Bv);
        o.z = fmaf((float)hi.h[0], A, Bv);
        o.w = fmaf((float)hi.h[1], A, Bv);
        op[k * 256] = o;
    }
}

// Fallback helpers (ws too small for gs): consts kernel + direct erf pass
__global__ void k_consts(const unsigned* __restrict__ gmm, float* __restrict__ ab) {
    int t = threadIdx.x;                       // 64 threads
    float mn = decf(gmm[t]);
    float mx = decf(gmm[TT + t]) - mn;
    float inv = 1.0f / ((mx != 0.0f) ? mx : 1e-5f);
    ab[t]      = inv;
    ab[TT + t] = -mn * SUMW * inv;
}

__global__ __launch_bounds__(256) void k_pass2_direct(const float* __restrict__ x,
                                                      const float* __restrict__ ab,
                                                      float* __restrict__ out) {
    __shared__ float sA[TT], sB[TT];
    const int tid = threadIdx.x;
    if (tid < TT)          sA[tid] = ab[tid];
    else if (tid < 2 * TT) sB[tid - TT] = ab[tid];
    __syncthreads();

    const int pix = blockIdx.x * 256 + tid;    // < 401408 = 8*HW
    const int b  = pix / HW;
    const int hw = pix - b * HW;
    const float* x0 = x + (size_t)(b * 3) * (TT * (size_t)HW) + hw;
    const float* x1 = x0 + (size_t)TT * HW;
    const float* x2 = x1 + (size_t)TT * HW;
    float* op = out + (size_t)b * (68 * (size_t)HW) + hw;

    op[0] = 0.f; op[HW] = 0.f; op[2 * (size_t)HW] = 0.f; op[3 * (size_t)HW] = 0.f;
    op += 4 * (size_t)HW;

    float a0 = x0[0], a1 = x0[HW], a2 = x0[2*HW], a3 = x0[3*HW], a4 = x0[4*HW];
    float b0 = x1[0], b1 = x1[HW], b2 = x1[2*HW], b3 = x1[3*HW], b4 = x1[4*HW];
    float c0 = x2[0], c1 = x2[HW], c2 = x2[2*HW], c3 = x2[3*HW], c4 = x2[4*HW];

    auto emit = [&](int t, float ra, float rb, float rc) {
        float gsv = 0.2989f * gelu_erf(ra) + 0.587f * gelu_erf(rb) + 0.114f * gelu_erf(rc);
        op[(size_t)t * HW] = fmaf(gsv, sA[t], sB[t]);
    };

    for (int t = 0; t < 59; ++t) {
        emit(t, 4.f*(a4-a0) + 2.f*(a3-a1), 4.f*(b4-b0) + 2.f*(b3-b1), 4.f*(c4-c0) + 2.f*(c3-c1));
        a0=a1; a1=a2; a2=a3; a3=a4; a4 = x0[(size_t)(t+5)*HW];
        b0=b1; b1=b2; b2=b3; b3=b4; b4 = x1[(size_t)(t+5)*HW];
        c0=c1; c1=c2; c2=c3; c3=c4; c4 = x2[(size_t)(t+5)*HW];
    }
    emit(59, 4.f*(a4-a0) + 2.f*(a3-a1), 4.f*(b4-b0) + 2.f*(b3-b1), 4.f*(c4-c0) + 2.f*(c3-c1));
    a0=a1; a1=a2; a2=a3; a3=a4; b0=b1; b1=b2; b2=b3; b3=b4; c0=c1; c1=c2; c2=c3; c3=c4;
    emit(60, 3.f*(a3-a0) + (a2-a1), 3.f*(b3-b0) + (b2-b1), 3.f*(c3-c0) + (c2-c1));
    a0=a1; a1=a2; a2=a3; b0=b1; b1=b2; b2=b3; c0=c1; c1=c2; c2=c3;
    emit(61, 2.f*(a2-a0), 2.f*(b2-b0), 2.f*(c2-c0));
    a0=a1; a1=a2; b0=b1; b1=b2; c0=c1; c1=c2;
    emit(62, a1-a0, b1-b0, c1-c0);
    op[63 * (size_t)HW] = sB[63];
}

extern "C" void kernel_launch(void* const* d_in, const int* in_sizes, int n_in,
                              void* d_out, int out_size, void* d_ws, size_t ws_size,
                              hipStream_t stream) {
    const float* x = (const float*)d_in[0];
    float* out = (float*)d_out;
    unsigned* gmm = (unsigned*)d_ws;                       // 128 u32
    float* ab = (float*)d_ws + 128;                        // 128 f32 (fallback only)
    unsigned* gs = (unsigned*)((char*)d_ws + 1024);
    const size_t need = 1024 + (size_t)8 * TT * (size_t)HW * 2;   // ~51.4 MB

    // init gmm: 0xFF... == encoded +inf sentinel (min half), 0x00... < all encodings (max half)
    hipMemsetAsync(gmm, 0xFF, TT * sizeof(unsigned), stream);
    hipMemsetAsync(gmm + TT, 0x00, TT * sizeof(unsigned), stream);

    if (ws_size >= need) {
        k_pass1<true><<<NB1, 256, 0, stream>>>(x, gmm, gs);
        k_pass3<<<NB3, 256, 0, stream>>>(gs, gmm, out);
    } else {
        k_pass1<false><<<NB1, 256, 0, stream>>>(x, gmm, nullptr);
        k_consts<<<1, 64, 0, stream>>>(gmm, ab);
        k_pass2_direct<<<1568, 256, 0, stream>>>(x, ab, out);
    }
}